// Round 4
// baseline (29.603 us; speedup 1.0000x reference)
//
#include <hip/hip_runtime.h>

// JaggedAppend: out = concat_i( values[seg_i] ++ suffix_mat[i] )
// One block per segment; float4 interior (src/dst share alignment phase since
// new_start - prev_old = seg*1024B). R4: nontemporal stores for the output
// stream (write-once, never re-read) so the input arrays stay L3-resident
// across graph replays instead of being evicted by 75 MB of write traffic.
// Uses clang ext_vector_type (native vector) — __builtin_nontemporal_store
// rejects HIP_vector_type structs.

#define SUF 256

typedef float floatx4 __attribute__((ext_vector_type(4)));

__global__ void jagged_append_kernel(const float* __restrict__ values,
                                     const int* __restrict__ prefix_sum,
                                     const float* __restrict__ suffix,
                                     float* __restrict__ out,
                                     int B) {
    const int seg = blockIdx.x;
    if (seg >= B) return;
    const int tid = threadIdx.x;
    const int nthr = blockDim.x;

    const long long prev_old = (seg > 0) ? (long long)prefix_sum[seg - 1] : 0ll;
    const long long end_old  = (long long)prefix_sum[seg];
    const long long seg_len  = end_old - prev_old;
    const long long new_start = prev_old + (long long)seg * SUF;

    const float* __restrict__ src = values + prev_old;
    float* __restrict__ dst = out + new_start;

    // Scalar head to reach 16B alignment (same phase on src and dst).
    long long head = (4 - (new_start & 3)) & 3;
    if (head > seg_len) head = seg_len;
    if (tid < head) __builtin_nontemporal_store(src[tid], &dst[tid]);

    // Aligned float4 interior (native vector type for nontemporal builtin).
    const long long nvec = (seg_len - head) >> 2;
    const floatx4* __restrict__ vsrc = (const floatx4*)(src + head);
    floatx4* __restrict__ vdst = (floatx4*)(dst + head);
    for (long long v = tid; v < nvec; v += nthr) {
        floatx4 val = vsrc[v];
        __builtin_nontemporal_store(val, &vdst[v]);
    }

    // Scalar tail (<=3 elems).
    const long long tail_start = head + (nvec << 2);
    for (long long i = tail_start + tid; i < seg_len; i += nthr) {
        __builtin_nontemporal_store(src[i], &dst[i]);
    }

    // Suffix row: 256 floats, src aligned but dst phase arbitrary -> scalar.
    const float* __restrict__ sfx = suffix + (long long)seg * SUF;
    float* __restrict__ sdst = dst + seg_len;
    for (int i = tid; i < SUF; i += nthr) {
        __builtin_nontemporal_store(sfx[i], &sdst[i]);
    }
}

extern "C" void kernel_launch(void* const* d_in, const int* in_sizes, int n_in,
                              void* d_out, int out_size, void* d_ws, size_t ws_size,
                              hipStream_t stream) {
    const float* values     = (const float*)d_in[0];
    const int*   prefix_sum = (const int*)d_in[1];
    const float* suffix     = (const float*)d_in[2];
    float* out = (float*)d_out;

    const int B = in_sizes[1];  // 8192 segments

    jagged_append_kernel<<<B, 256, 0, stream>>>(values, prefix_sum, suffix, out, B);
}